// Round 1
// baseline (3165.775 us; speedup 1.0000x reference)
//
#include <hip/hip_runtime.h>

// ---------------- types / helpers ----------------
typedef __attribute__((ext_vector_type(8))) short short8;
typedef __attribute__((ext_vector_type(4))) float f32x4;
typedef unsigned short u16;

#define N_TOK   1536
#define DMODEL  1024
#define NHEAD   16
#define DHEAD   64
#define NCTX    512
#define INNERD  2730
#define INNERP  2752   // K-padded inner
#define FF1P    5504   // N-padded 2*inner
#define VOCAB   8192

__device__ __forceinline__ u16 f2b(float f) {
  union { float f; unsigned u; } v; v.f = f;
  unsigned r = (v.u >> 16) & 1u;
  return (u16)((v.u + 0x7fffu + r) >> 16);
}

// ---------------- weight convert+transpose: f32 [z][K][Nw] -> bf16 [z][.. ][Kpad], out[n][k]=in[k][n]
__global__ __launch_bounds__(256) void conv_t(
    const float* __restrict__ in, u16* __restrict__ out,
    int K, int Nw, int Kpad, int Nbound, long long zin, long long zout)
{
  const float* inl = in + (size_t)blockIdx.z * zin;
  u16* outl = out + (size_t)blockIdx.z * zout;
  __shared__ float tile[32][33];
  int k0 = blockIdx.x * 32, n0 = blockIdx.y * 32;
  int tx = threadIdx.x, ty = threadIdx.y; // 32 x 8
#pragma unroll
  for (int i = 0; i < 4; i++) {
    int k = k0 + ty + i * 8, n = n0 + tx;
    tile[ty + i * 8][tx] = (k < K && n < Nw) ? inl[(size_t)k * Nw + n] : 0.0f;
  }
  __syncthreads();
#pragma unroll
  for (int i = 0; i < 4; i++) {
    int n = n0 + ty + i * 8, k = k0 + tx;
    if (n < Nbound && k < Kpad) outl[(size_t)n * Kpad + k] = f2b(tile[tx][ty + i * 8]);
  }
}

// ---------------- embeddings ----------------
__global__ void embed_img(const int* __restrict__ x, const float* __restrict__ temb,
                          const float* __restrict__ pemb, float* __restrict__ h) {
  int n = blockIdx.x; int tok = x[n]; int d4 = threadIdx.x;
  float4 a = *(const float4*)&temb[(size_t)tok * DMODEL + d4 * 4];
  float4 b = *(const float4*)&pemb[(size_t)n * DMODEL + d4 * 4];
  float4 o; o.x = a.x + b.x; o.y = a.y + b.y; o.z = a.z + b.z; o.w = a.w + b.w;
  *(float4*)&h[(size_t)n * DMODEL + d4 * 4] = o;
}

__global__ void embed_ctx(const int* __restrict__ ids, const float* __restrict__ temb,
                          const float* __restrict__ pemb, u16* __restrict__ ctxb) {
  int n = blockIdx.x; int tok = ids[n]; int d4 = threadIdx.x;
  float4 a = *(const float4*)&temb[(size_t)tok * DMODEL + d4 * 4];
  float4 b = *(const float4*)&pemb[(size_t)n * DMODEL + d4 * 4];
  u16* o = ctxb + (size_t)n * DMODEL + d4 * 4;
  o[0] = f2b(a.x + b.x); o[1] = f2b(a.y + b.y); o[2] = f2b(a.z + b.z); o[3] = f2b(a.w + b.w);
}

// ---------------- LayerNorm -> bf16 (with zero K-padding) ----------------
__global__ __launch_bounds__(256) void ln_bf16(
    const float* __restrict__ X, int ldin, const float* __restrict__ g,
    u16* __restrict__ Y, int ldout, int C, int Cpad)
{
  int row = blockIdx.x;
  const float* x = X + (size_t)row * ldin;
  float s = 0.f, sq = 0.f;
  for (int ci = threadIdx.x; ci < C; ci += 256) { float v = x[ci]; s += v; sq += v * v; }
#pragma unroll
  for (int m = 1; m < 64; m <<= 1) { s += __shfl_xor(s, m, 64); sq += __shfl_xor(sq, m, 64); }
  __shared__ float red[2][4];
  int w = threadIdx.x >> 6;
  if ((threadIdx.x & 63) == 0) { red[0][w] = s; red[1][w] = sq; }
  __syncthreads();
  s = red[0][0] + red[0][1] + red[0][2] + red[0][3];
  sq = red[1][0] + red[1][1] + red[1][2] + red[1][3];
  float mean = s / C;
  float var = sq / C - mean * mean;
  float rstd = rsqrtf(var + 1e-5f);
  u16* y = Y + (size_t)row * ldout;
  for (int ci = threadIdx.x; ci < C; ci += 256) y[ci] = f2b((x[ci] - mean) * rstd * g[ci]);
  for (int ci = C + threadIdx.x; ci < Cpad; ci += 256) y[ci] = 0;
}

// ---------------- GEMM: C(M,N) f32 = A(M,K)bf16 @ Bt(N,K)bf16, tiles 128x128, BK=64 ----------------
template <bool ACCUM>
__global__ __launch_bounds__(256) void gemm_bt(
    const u16* __restrict__ A, const u16* __restrict__ Bt,
    float* __restrict__ C, int ldc, int M, int N, int K, int lda, int ldb)
{
  __shared__ __align__(16) short As[128 * 72];
  __shared__ __align__(16) short Bs[128 * 72];
  int tid = threadIdx.x;
  int bm = blockIdx.x, bn = blockIdx.y;
  int lane = tid & 63, w = tid >> 6;
  int wm = (w >> 1) * 64, wn = (w & 1) * 64;
  int rl = lane & 15, quad = lane >> 4;
  f32x4 acc[4][4];
#pragma unroll
  for (int i = 0; i < 4; i++)
#pragma unroll
    for (int j = 0; j < 4; j++) acc[i][j] = (f32x4)(0.f);
  const int rowA0 = bm * 128, rowB0 = bn * 128;

  for (int k0 = 0; k0 < K; k0 += 64) {
    __syncthreads();
#pragma unroll
    for (int i = 0; i < 4; i++) {
      int ch = tid + 256 * i;
      int r = ch >> 3, c8 = (ch & 7) * 8;
      *(short8*)&As[r * 72 + c8] = *(const short8*)(A + (size_t)(rowA0 + r) * lda + k0 + c8);
      *(short8*)&Bs[r * 72 + c8] = *(const short8*)(Bt + (size_t)(rowB0 + r) * ldb + k0 + c8);
    }
    __syncthreads();
#pragma unroll
    for (int kk = 0; kk < 64; kk += 32) {
      int kq = kk + quad * 8;
      short8 af[4], bfr[4];
#pragma unroll
      for (int t = 0; t < 4; t++) {
        af[t]  = *(const short8*)&As[(wm + t * 16 + rl) * 72 + kq];
        bfr[t] = *(const short8*)&Bs[(wn + t * 16 + rl) * 72 + kq];
      }
#pragma unroll
      for (int mt = 0; mt < 4; mt++)
#pragma unroll
        for (int nt = 0; nt < 4; nt++)
          acc[mt][nt] = __builtin_amdgcn_mfma_f32_16x16x32_bf16(af[mt], bfr[nt], acc[mt][nt], 0, 0, 0);
    }
  }
#pragma unroll
  for (int mt = 0; mt < 4; mt++)
#pragma unroll
    for (int nt = 0; nt < 4; nt++)
#pragma unroll
      for (int r = 0; r < 4; r++) {
        int row = rowA0 + wm + mt * 16 + quad * 4 + r;
        int col = rowB0 + wn + nt * 16 + rl;
        if (ACCUM) C[(size_t)row * ldc + col] += acc[mt][nt][r];
        else       C[(size_t)row * ldc + col]  = acc[mt][nt][r];
      }
}

// ---------------- k/v prep: prepend null token, l2norm(k)*ks; out [H][Lk][64] ----------------
__global__ void qkv_prep(const float* __restrict__ kvb, int ldkv,   // k at kvb[j*ldkv+h*64], v at +1024
                         const float* __restrict__ nullkv,          // [2][16][64]
                         const float* __restrict__ ks,
                         float* __restrict__ Kn, float* __restrict__ Vn, int Lk)
{
  int w = threadIdx.x >> 6, d = threadIdx.x & 63;
  int idx = blockIdx.x * 4 + w;
  if (idx >= NHEAD * Lk) return;
  int h = idx / Lk, j = idx - h * Lk;
  float k, v;
  if (j == 0) { k = nullkv[h * 64 + d]; v = nullkv[NHEAD * 64 + h * 64 + d]; }
  else {
    const float* row = kvb + (size_t)(j - 1) * ldkv + h * 64;
    k = row[d]; v = row[1024 + d];
  }
  float ssq = k * k;
#pragma unroll
  for (int m = 1; m < 64; m <<= 1) ssq += __shfl_xor(ssq, m, 64);
  float kn = k * (1.0f / fmaxf(sqrtf(ssq), 1e-12f)) * ks[d];
  Kn[(size_t)idx * 64 + d] = kn;
  Vn[(size_t)idx * 64 + d] = v;
}

// ---------------- fused attention: q l2norm*qs*8, softmax (no max; |s|<=8), PV; bf16 out ----------------
__global__ __launch_bounds__(256) void attn(
    const float* __restrict__ Qraw, int ldq,
    const float* __restrict__ Kn, const float* __restrict__ Vn,
    const float* __restrict__ qs, u16* __restrict__ Ob, int Lk)
{
  __shared__ __align__(16) float Kl[64 * 68];
  __shared__ __align__(16) float Vl[64 * 68];
  int tid = threadIdx.x;
  int r = tid >> 2, c = tid & 3;
  int h = blockIdx.y;
  int qi = blockIdx.x * 64 + r;
  float qn[64];
  {
    const float* qp = Qraw + (size_t)qi * ldq + h * 64;
    float ssq = 0.f;
#pragma unroll
    for (int i = 0; i < 16; i++) {
      float4 t = *(const float4*)&qp[i * 4];
      qn[4 * i] = t.x; qn[4 * i + 1] = t.y; qn[4 * i + 2] = t.z; qn[4 * i + 3] = t.w;
      ssq += t.x * t.x + t.y * t.y + t.z * t.z + t.w * t.w;
    }
    float inv = 8.0f / fmaxf(sqrtf(ssq), 1e-12f);   // fold sim*SCALE into q
#pragma unroll
    for (int i = 0; i < 64; i++) qn[i] *= inv * qs[i];
  }
  float acc[64];
#pragma unroll
  for (int i = 0; i < 64; i++) acc[i] = 0.f;
  float lsum = 0.f;
  const float* Kh = Kn + (size_t)h * Lk * 64;
  const float* Vh = Vn + (size_t)h * Lk * 64;

  for (int j0 = 0; j0 < Lk; j0 += 64) {
    int nrows = Lk - j0; if (nrows > 64) nrows = 64;
    __syncthreads();
#pragma unroll
    for (int i = 0; i < 4; i++) {
      int ch = tid + 256 * i;
      int rr = ch >> 4, cc = (ch & 15) * 4;
      if (rr < nrows) {
        *(float4*)&Kl[rr * 68 + cc] = *(const float4*)&Kh[(size_t)(j0 + rr) * 64 + cc];
        *(float4*)&Vl[rr * 68 + cc] = *(const float4*)&Vh[(size_t)(j0 + rr) * 64 + cc];
      }
    }
    __syncthreads();
    for (int t = c; t < nrows; t += 4) {
      const float4* kr = (const float4*)&Kl[t * 68];
      float s = 0.f;
#pragma unroll
      for (int i = 0; i < 16; i++) {
        float4 kk = kr[i];
        s += qn[4 * i] * kk.x + qn[4 * i + 1] * kk.y + qn[4 * i + 2] * kk.z + qn[4 * i + 3] * kk.w;
      }
      float p = __expf(s);
      lsum += p;
      const float4* vr = (const float4*)&Vl[t * 68];
#pragma unroll
      for (int i = 0; i < 16; i++) {
        float4 vv = vr[i];
        acc[4 * i] += p * vv.x; acc[4 * i + 1] += p * vv.y;
        acc[4 * i + 2] += p * vv.z; acc[4 * i + 3] += p * vv.w;
      }
    }
  }
  lsum += __shfl_xor(lsum, 1, 64);
  lsum += __shfl_xor(lsum, 2, 64);
#pragma unroll
  for (int i = 0; i < 64; i++) {
    acc[i] += __shfl_xor(acc[i], 1, 64);
    acc[i] += __shfl_xor(acc[i], 2, 64);
  }
  if (c == 0) {
    float invl = 1.0f / lsum;
    u16* op = Ob + (size_t)qi * DMODEL + h * 64;
#pragma unroll
    for (int i = 0; i < 64; i++) op[i] = f2b(acc[i] * invl);
  }
}

// ---------------- GEGLU activation in-place: h1[r][i] = gate * gelu_exact(a) ----------------
__global__ void geglu(float* __restrict__ h1) {
  int row = blockIdx.y;
  int i = blockIdx.x * 256 + threadIdx.x;
  if (i < INNERD) {
    float* p = h1 + (size_t)row * FF1P;
    float a = p[i], gate = p[INNERD + i];
    float ge = 0.5f * a * (1.0f + erff(a * 0.70710678118654752f));
    p[i] = gate * ge;
  }
}

// ---------------- host ----------------
extern "C" void kernel_launch(void* const* d_in, const int* in_sizes, int n_in,
                              void* d_out, int out_size, void* d_ws, size_t ws_size,
                              hipStream_t stream) {
  const int*   x        = (const int*)d_in[0];
  const int*   cond_ids = (const int*)d_in[1];
  const float* token_emb      = (const float*)d_in[2];
  const float* pos_emb        = (const float*)d_in[3];
  const float* cond_token_emb = (const float*)d_in[4];
  const float* cond_pos_emb   = (const float*)d_in[5];
  const float* sa_g   = (const float*)d_in[6];
  const float* sa_wq  = (const float*)d_in[7];
  const float* sa_wkv = (const float*)d_in[8];
  const float* sa_null= (const float*)d_in[9];
  const float* sa_qs  = (const float*)d_in[10];
  const float* sa_ks  = (const float*)d_in[11];
  const float* sa_wo  = (const float*)d_in[12];
  const float* ca_g   = (const float*)d_in[13];
  const float* ca_wq  = (const float*)d_in[14];
  const float* ca_wkv = (const float*)d_in[15];
  const float* ca_null= (const float*)d_in[16];
  const float* ca_qs  = (const float*)d_in[17];
  const float* ca_ks  = (const float*)d_in[18];
  const float* ca_wo  = (const float*)d_in[19];
  const float* ff_g1  = (const float*)d_in[20];
  const float* ff_w1  = (const float*)d_in[21];
  const float* ff_g2  = (const float*)d_in[22];
  const float* ff_w2  = (const float*)d_in[23];
  const float* final_g  = (const float*)d_in[24];
  const float* w_logits = (const float*)d_in[25];

  char* base = (char*)d_ws; size_t off = 0;
  auto alloc = [&](size_t bytes) -> void* {
    void* r = base + off; off = (off + bytes + 255) & ~(size_t)255; return r;
  };
  u16* sa_qkv_t = (u16*)alloc((size_t)4 * 3072 * 1024 * 2);
  u16* sa_wo_t  = (u16*)alloc((size_t)4 * 1024 * 1024 * 2);
  u16* ca_wq_t  = (u16*)alloc((size_t)4 * 1024 * 1024 * 2);
  u16* ca_wkv_t = (u16*)alloc((size_t)4 * 2048 * 1024 * 2);
  u16* ca_wo_t  = (u16*)alloc((size_t)4 * 1024 * 1024 * 2);
  u16* ff_w1_t  = (u16*)alloc((size_t)4 * FF1P * 1024 * 2);
  u16* ff_w2_t  = (u16*)alloc((size_t)4 * 1024 * INNERP * 2);
  u16* logits_t = (u16*)alloc((size_t)VOCAB * 1024 * 2);
  float* h    = (float*)alloc((size_t)N_TOK * DMODEL * 4);
  u16*   ctxb = (u16*)alloc((size_t)NCTX * DMODEL * 2);
  u16*   xnb  = (u16*)alloc((size_t)N_TOK * INNERP * 2);
  float* qkv  = (float*)alloc((size_t)N_TOK * 3072 * 4);
  float* Kn   = (float*)alloc((size_t)NHEAD * (N_TOK + 1) * 64 * 4);
  float* Vn   = (float*)alloc((size_t)NHEAD * (N_TOK + 1) * 64 * 4);
  u16*   ob   = (u16*)alloc((size_t)N_TOK * DMODEL * 2);
  float* h1   = (float*)alloc((size_t)N_TOK * FF1P * 4);
  (void)ws_size; (void)in_sizes; (void)n_in; (void)out_size;

  dim3 tb(32, 8);
  // weight convert+transpose (z = layer)
  conv_t<<<dim3(32, 32, 4), tb, 0, stream>>>(sa_wq,  sa_qkv_t,              1024, 1024, 1024, 1024, 1024LL*1024, 3072LL*1024);
  conv_t<<<dim3(32, 64, 4), tb, 0, stream>>>(sa_wkv, sa_qkv_t + 1024*1024,  1024, 2048, 1024, 2048, 1024LL*2048, 3072LL*1024);
  conv_t<<<dim3(32, 32, 4), tb, 0, stream>>>(sa_wo,  sa_wo_t,               1024, 1024, 1024, 1024, 1024LL*1024, 1024LL*1024);
  conv_t<<<dim3(32, 32, 4), tb, 0, stream>>>(ca_wq,  ca_wq_t,               1024, 1024, 1024, 1024, 1024LL*1024, 1024LL*1024);
  conv_t<<<dim3(32, 64, 4), tb, 0, stream>>>(ca_wkv, ca_wkv_t,              1024, 2048, 1024, 2048, 1024LL*2048, 2048LL*1024);
  conv_t<<<dim3(32, 32, 4), tb, 0, stream>>>(ca_wo,  ca_wo_t,               1024, 1024, 1024, 1024, 1024LL*1024, 1024LL*1024);
  conv_t<<<dim3(32, 172, 4), tb, 0, stream>>>(ff_w1, ff_w1_t,               1024, 5460, 1024, FF1P, 1024LL*5460, (long long)FF1P*1024);
  conv_t<<<dim3(86, 32, 4), tb, 0, stream>>>(ff_w2,  ff_w2_t,               INNERD, 1024, INNERP, 1024, (long long)INNERD*1024, 1024LL*INNERP);
  conv_t<<<dim3(32, 256, 1), tb, 0, stream>>>(w_logits, logits_t,           1024, VOCAB, 1024, VOCAB, 0, 0);

  // embeddings
  embed_img<<<dim3(N_TOK), dim3(256), 0, stream>>>(x, token_emb, pos_emb, h);
  embed_ctx<<<dim3(NCTX), dim3(256), 0, stream>>>(cond_ids, cond_token_emb, cond_pos_emb, ctxb);

  for (int l = 0; l < 4; l++) {
    const u16* sqkv = sa_qkv_t + (size_t)l * 3072 * 1024;
    const u16* swo  = sa_wo_t  + (size_t)l * 1024 * 1024;
    const u16* cwq  = ca_wq_t  + (size_t)l * 1024 * 1024;
    const u16* cwkv = ca_wkv_t + (size_t)l * 2048 * 1024;
    const u16* cwo  = ca_wo_t  + (size_t)l * 1024 * 1024;
    const u16* fw1  = ff_w1_t  + (size_t)l * FF1P * 1024;
    const u16* fw2  = ff_w2_t  + (size_t)l * 1024 * INNERP;

    // ---- self-attention ----
    ln_bf16<<<dim3(N_TOK), dim3(256), 0, stream>>>(h, DMODEL, sa_g + l * DMODEL, xnb, DMODEL, DMODEL, DMODEL);
    gemm_bt<false><<<dim3(12, 24), dim3(256), 0, stream>>>(xnb, sqkv, qkv, 3072, N_TOK, 3072, 1024, 1024, 1024);
    qkv_prep<<<dim3((NHEAD * 1537 + 3) / 4), dim3(256), 0, stream>>>(qkv + 1024, 3072, sa_null + l * 2048, sa_ks + l * 64, Kn, Vn, 1537);
    attn<<<dim3(24, NHEAD), dim3(256), 0, stream>>>(qkv, 3072, Kn, Vn, sa_qs + l * 64, ob, 1537);
    gemm_bt<true><<<dim3(12, 8), dim3(256), 0, stream>>>(ob, swo, h, 1024, N_TOK, 1024, 1024, 1024, 1024);

    // ---- cross-attention ----
    ln_bf16<<<dim3(N_TOK), dim3(256), 0, stream>>>(h, DMODEL, ca_g + l * DMODEL, xnb, DMODEL, DMODEL, DMODEL);
    gemm_bt<false><<<dim3(12, 8), dim3(256), 0, stream>>>(xnb, cwq, qkv, 3072, N_TOK, 1024, 1024, 1024, 1024);
    gemm_bt<false><<<dim3(4, 16), dim3(256), 0, stream>>>(ctxb, cwkv, qkv + 1024, 3072, NCTX, 2048, 1024, 1024, 1024);
    qkv_prep<<<dim3((NHEAD * 513 + 3) / 4), dim3(256), 0, stream>>>(qkv + 1024, 3072, ca_null + l * 2048, ca_ks + l * 64, Kn, Vn, 513);
    attn<<<dim3(24, NHEAD), dim3(256), 0, stream>>>(qkv, 3072, Kn, Vn, ca_qs + l * 64, ob, 513);
    gemm_bt<true><<<dim3(12, 8), dim3(256), 0, stream>>>(ob, cwo, h, 1024, N_TOK, 1024, 1024, 1024, 1024);

    // ---- GEGLU feedforward ----
    ln_bf16<<<dim3(N_TOK), dim3(256), 0, stream>>>(h, DMODEL, ff_g1 + l * DMODEL, xnb, DMODEL, DMODEL, DMODEL);
    gemm_bt<false><<<dim3(12, 43), dim3(256), 0, stream>>>(xnb, fw1, h1, FF1P, N_TOK, FF1P, 1024, 1024, 1024);
    geglu<<<dim3(11, N_TOK), dim3(256), 0, stream>>>(h1);
    ln_bf16<<<dim3(N_TOK), dim3(256), 0, stream>>>(h1, FF1P, ff_g2 + l * INNERD, xnb, INNERP, INNERD, INNERP);
    gemm_bt<true><<<dim3(12, 8), dim3(256), 0, stream>>>(xnb, fw2, h, 1024, N_TOK, 1024, INNERP, INNERP, INNERP);
  }

  // ---- final LN + logits ----
  ln_bf16<<<dim3(N_TOK), dim3(256), 0, stream>>>(h, DMODEL, final_g, xnb, DMODEL, DMODEL, DMODEL);
  gemm_bt<false><<<dim3(12, 64), dim3(256), 0, stream>>>(xnb, logits_t, (float*)d_out, VOCAB, N_TOK, VOCAB, 1024, 1024, 1024);
}

// Round 2
// 2305.849 us; speedup vs baseline: 1.3729x; 1.3729x over previous
//
#include <hip/hip_runtime.h>

// ---------------- types / helpers ----------------
typedef __attribute__((ext_vector_type(8))) short short8;
typedef __attribute__((ext_vector_type(4))) float f32x4;
typedef unsigned short u16;

#define N_TOK   1536
#define DMODEL  1024
#define NHEAD   16
#define DHEAD   64
#define NCTX    512
#define INNERD  2730
#define INNERP  2752   // K-padded inner
#define FF1P    5504   // N-padded 2*inner
#define VOCAB   8192

__device__ __forceinline__ u16 f2b(float f) {
  union { float f; unsigned u; } v; v.f = f;
  unsigned r = (v.u >> 16) & 1u;
  return (u16)((v.u + 0x7fffu + r) >> 16);
}

// ---------------- weight convert+transpose: f32 [z][K][Nw] -> bf16 [z][..][Kpad], out[n][k]=in[k][n]
__global__ __launch_bounds__(256) void conv_t(
    const float* __restrict__ in, u16* __restrict__ out,
    int K, int Nw, int Kpad, int Nbound, long long zin, long long zout)
{
  const float* inl = in + (size_t)blockIdx.z * zin;
  u16* outl = out + (size_t)blockIdx.z * zout;
  __shared__ float tile[32][33];
  int k0 = blockIdx.x * 32, n0 = blockIdx.y * 32;
  int tx = threadIdx.x, ty = threadIdx.y; // 32 x 8
#pragma unroll
  for (int i = 0; i < 4; i++) {
    int k = k0 + ty + i * 8, n = n0 + tx;
    tile[ty + i * 8][tx] = (k < K && n < Nw) ? inl[(size_t)k * Nw + n] : 0.0f;
  }
  __syncthreads();
#pragma unroll
  for (int i = 0; i < 4; i++) {
    int n = n0 + ty + i * 8, k = k0 + tx;
    if (n < Nbound && k < Kpad) outl[(size_t)n * Kpad + k] = f2b(tile[tx][ty + i * 8]);
  }
}

// ---------------- embeddings ----------------
__global__ void embed_img(const int* __restrict__ x, const float* __restrict__ temb,
                          const float* __restrict__ pemb, float* __restrict__ h) {
  int n = blockIdx.x; int tok = x[n]; int d4 = threadIdx.x;
  float4 a = *(const float4*)&temb[(size_t)tok * DMODEL + d4 * 4];
  float4 b = *(const float4*)&pemb[(size_t)n * DMODEL + d4 * 4];
  float4 o; o.x = a.x + b.x; o.y = a.y + b.y; o.z = a.z + b.z; o.w = a.w + b.w;
  *(float4*)&h[(size_t)n * DMODEL + d4 * 4] = o;
}

__global__ void embed_ctx(const int* __restrict__ ids, const float* __restrict__ temb,
                          const float* __restrict__ pemb, u16* __restrict__ ctxb) {
  int n = blockIdx.x; int tok = ids[n]; int d4 = threadIdx.x;
  float4 a = *(const float4*)&temb[(size_t)tok * DMODEL + d4 * 4];
  float4 b = *(const float4*)&pemb[(size_t)n * DMODEL + d4 * 4];
  u16* o = ctxb + (size_t)n * DMODEL + d4 * 4;
  o[0] = f2b(a.x + b.x); o[1] = f2b(a.y + b.y); o[2] = f2b(a.z + b.z); o[3] = f2b(a.w + b.w);
}

// ---------------- LayerNorm -> bf16 (with zero K-padding) ----------------
__global__ __launch_bounds__(256) void ln_bf16(
    const float* __restrict__ X, int ldin, const float* __restrict__ g,
    u16* __restrict__ Y, int ldout, int C, int Cpad)
{
  int row = blockIdx.x;
  const float* x = X + (size_t)row * ldin;
  float s = 0.f, sq = 0.f;
  for (int ci = threadIdx.x; ci < C; ci += 256) { float v = x[ci]; s += v; sq += v * v; }
#pragma unroll
  for (int m = 1; m < 64; m <<= 1) { s += __shfl_xor(s, m, 64); sq += __shfl_xor(sq, m, 64); }
  __shared__ float red[2][4];
  int w = threadIdx.x >> 6;
  if ((threadIdx.x & 63) == 0) { red[0][w] = s; red[1][w] = sq; }
  __syncthreads();
  s = red[0][0] + red[0][1] + red[0][2] + red[0][3];
  sq = red[1][0] + red[1][1] + red[1][2] + red[1][3];
  float mean = s / C;
  float var = sq / C - mean * mean;
  float rstd = rsqrtf(var + 1e-5f);
  u16* y = Y + (size_t)row * ldout;
  for (int ci = threadIdx.x; ci < C; ci += 256) y[ci] = f2b((x[ci] - mean) * rstd * g[ci]);
  for (int ci = C + threadIdx.x; ci < Cpad; ci += 256) y[ci] = 0;
}

// ---------------- GEMM: C(M,N) f32 = A(M,K)bf16 @ Bt(N,K)bf16, tiles 128x128, BK=64 ----------------
template <bool ACCUM>
__global__ __launch_bounds__(256) void gemm_bt(
    const u16* __restrict__ A, const u16* __restrict__ Bt,
    float* __restrict__ C, int ldc, int M, int N, int K, int lda, int ldb)
{
  __shared__ __align__(16) short As[128 * 72];
  __shared__ __align__(16) short Bs[128 * 72];
  int tid = threadIdx.x;
  int bm = blockIdx.x, bn = blockIdx.y;
  int lane = tid & 63, w = tid >> 6;
  int wm = (w >> 1) * 64, wn = (w & 1) * 64;
  int rl = lane & 15, quad = lane >> 4;
  f32x4 acc[4][4];
#pragma unroll
  for (int i = 0; i < 4; i++)
#pragma unroll
    for (int j = 0; j < 4; j++) acc[i][j] = (f32x4)(0.f);
  const int rowA0 = bm * 128, rowB0 = bn * 128;

  for (int k0 = 0; k0 < K; k0 += 64) {
    __syncthreads();
#pragma unroll
    for (int i = 0; i < 4; i++) {
      int ch = tid + 256 * i;
      int r = ch >> 3, c8 = (ch & 7) * 8;
      *(short8*)&As[r * 72 + c8] = *(const short8*)(A + (size_t)(rowA0 + r) * lda + k0 + c8);
      *(short8*)&Bs[r * 72 + c8] = *(const short8*)(Bt + (size_t)(rowB0 + r) * ldb + k0 + c8);
    }
    __syncthreads();
#pragma unroll
    for (int kk = 0; kk < 64; kk += 32) {
      int kq = kk + quad * 8;
      short8 af[4], bfr[4];
#pragma unroll
      for (int t = 0; t < 4; t++) {
        af[t]  = *(const short8*)&As[(wm + t * 16 + rl) * 72 + kq];
        bfr[t] = *(const short8*)&Bs[(wn + t * 16 + rl) * 72 + kq];
      }
#pragma unroll
      for (int mt = 0; mt < 4; mt++)
#pragma unroll
        for (int nt = 0; nt < 4; nt++)
          acc[mt][nt] = __builtin_amdgcn_mfma_f32_16x16x32_bf16(af[mt], bfr[nt], acc[mt][nt], 0, 0, 0);
    }
  }
#pragma unroll
  for (int mt = 0; mt < 4; mt++)
#pragma unroll
    for (int nt = 0; nt < 4; nt++)
#pragma unroll
      for (int r = 0; r < 4; r++) {
        int row = rowA0 + wm + mt * 16 + quad * 4 + r;
        int col = rowB0 + wn + nt * 16 + rl;
        if (ACCUM) C[(size_t)row * ldc + col] += acc[mt][nt][r];
        else       C[(size_t)row * ldc + col]  = acc[mt][nt][r];
      }
}

// ---------------- prep Q: l2norm * qs * 8 -> bf16 Qn[h][1536][64] ----------------
__global__ __launch_bounds__(256) void prep_q(
    const float* __restrict__ qkv, const float* __restrict__ qs, u16* __restrict__ Qn)
{
  int w = threadIdx.x >> 6, d = threadIdx.x & 63;
  int m = blockIdx.x * 4 + w;
  int h = blockIdx.y;
  float q = qkv[(size_t)m * 3072 + h * 64 + d];
  float ssq = q * q;
#pragma unroll
  for (int ms = 1; ms < 64; ms <<= 1) ssq += __shfl_xor(ssq, ms, 64);
  float qn = q * (8.0f / fmaxf(sqrtf(ssq), 1e-12f)) * qs[d];
  Qn[((size_t)h * N_TOK + m) * 64 + d] = f2b(qn);
}

// ---------------- prep K: null prepend, l2norm * ks -> bf16 Kn[h][Lkp][64]; zero rows j>=Lk ----
__global__ __launch_bounds__(256) void prep_k(
    const float* __restrict__ kvb, const float* __restrict__ nullkv,
    const float* __restrict__ ks, u16* __restrict__ Kn, int Lk, int Lkp)
{
  int w = threadIdx.x >> 6, d = threadIdx.x & 63;
  int j = blockIdx.x * 4 + w;
  int h = blockIdx.y;
  if (j >= Lkp) return;
  float k = 0.f;
  if (j == 0) k = nullkv[h * 64 + d];
  else if (j < Lk) k = kvb[(size_t)(j - 1) * 3072 + h * 64 + d];
  float ssq = k * k;
#pragma unroll
  for (int ms = 1; ms < 64; ms <<= 1) ssq += __shfl_xor(ssq, ms, 64);
  float kn = k * (1.0f / fmaxf(sqrtf(ssq), 1e-12f)) * ks[d];
  Kn[((size_t)h * Lkp + j) * 64 + d] = f2b(kn);
}

// ---------------- transpose V -> bf16 Vt[h][64][Lkp] (null at j=0, zeros j>=Lk) ----------------
__global__ __launch_bounds__(256) void transp_v(
    const float* __restrict__ qkv, const float* __restrict__ nullkv,
    u16* __restrict__ Vt, int Lk, int Lkp)
{
  __shared__ float tile[64][65];
  int h = blockIdx.y;
  int j0 = blockIdx.x * 64;
  int tid = threadIdx.x;
  {
    int jl = tid >> 2, dblk = (tid & 3) * 16;
    int j = j0 + jl;
#pragma unroll
    for (int i = 0; i < 16; i++) {
      int d = dblk + i;
      float v = 0.f;
      if (j == 0) v = nullkv[NHEAD * 64 + h * 64 + d];
      else if (j < Lk) v = qkv[(size_t)(j - 1) * 3072 + 2048 + h * 64 + d];
      tile[jl][d] = v;
    }
  }
  __syncthreads();
  {
    int d = tid >> 2, jblk = (tid & 3) * 16;
    u16 pk[16];
#pragma unroll
    for (int i = 0; i < 16; i++) pk[i] = f2b(tile[jblk + i][d]);
    u16* op = Vt + ((size_t)h * 64 + d) * Lkp + j0 + jblk;
    *(short8*)&op[0] = *(short8*)&pk[0];
    *(short8*)&op[8] = *(short8*)&pk[8];
  }
}

// ---------------- MFMA flash attention: 64 q-rows x 1 head per block, 4 waves x 16 rows ----
// S = Qn Kn^T (fp32 acc), p = exp(s) (no max; |s|<=8), P->LDS->A-frag, O += P Vt^T.
// Padded keys: K row = 0 => s=0 => p=1 exactly; Vt cols = 0; lsum -= pad.
__global__ __launch_bounds__(256) void attn_mfma(
    const u16* __restrict__ Qn, const u16* __restrict__ Kn, const u16* __restrict__ Vt,
    u16* __restrict__ Ob, int Lkp, int nk, float pad)
{
  __shared__ __align__(16) short Ps[4 * 16 * 72];
  int tid = threadIdx.x, w = tid >> 6, lane = tid & 63;
  int rl = lane & 15, quad = lane >> 4;
  int h = blockIdx.y;
  int m0 = blockIdx.x * 64 + w * 16;
  const u16* Qh = Qn + ((size_t)h * N_TOK + m0) * 64;
  const u16* Kh = Kn + (size_t)h * Lkp * 64;
  const u16* Vh = Vt + (size_t)h * 64 * Lkp;
  short* Pw = Ps + w * 16 * 72;

  short8 aq[2];
  aq[0] = *(const short8*)(Qh + rl * 64 + quad * 8);
  aq[1] = *(const short8*)(Qh + rl * 64 + 32 + quad * 8);
  f32x4 oacc[4];
#pragma unroll
  for (int dt = 0; dt < 4; dt++) oacc[dt] = (f32x4)(0.f);
  float lrow[4] = {0.f, 0.f, 0.f, 0.f};

  for (int kt = 0; kt < nk; kt++) {
    int j0 = kt * 64;
    short8 bk[4][2], bv[4][2];
#pragma unroll
    for (int nt = 0; nt < 4; nt++)
#pragma unroll
      for (int kc = 0; kc < 2; kc++)
        bk[nt][kc] = *(const short8*)(Kh + (size_t)(j0 + nt * 16 + rl) * 64 + kc * 32 + quad * 8);
#pragma unroll
    for (int dt = 0; dt < 4; dt++)
#pragma unroll
      for (int kc = 0; kc < 2; kc++)
        bv[dt][kc] = *(const short8*)(Vh + (size_t)(dt * 16 + rl) * Lkp + j0 + kc * 32 + quad * 8);

    f32x4 sacc[4];
#pragma unroll
    for (int nt = 0; nt < 4; nt++) sacc[nt] = (f32x4)(0.f);
#pragma unroll
    for (int kc = 0; kc < 2; kc++)
#pragma unroll
      for (int nt = 0; nt < 4; nt++)
        sacc[nt] = __builtin_amdgcn_mfma_f32_16x16x32_bf16(aq[kc], bk[nt][kc], sacc[nt], 0, 0, 0);

#pragma unroll
    for (int nt = 0; nt < 4; nt++)
#pragma unroll
      for (int r = 0; r < 4; r++) {
        float p = __expf(sacc[nt][r]);
        lrow[r] += p;
        Pw[(quad * 4 + r) * 72 + nt * 16 + rl] = (short)f2b(p);
      }
    __asm volatile("s_waitcnt lgkmcnt(0)" ::: "memory");
    short8 ap0 = *(const short8*)&Pw[rl * 72 + quad * 8];
    short8 ap1 = *(const short8*)&Pw[rl * 72 + 32 + quad * 8];
#pragma unroll
    for (int dt = 0; dt < 4; dt++) {
      oacc[dt] = __builtin_amdgcn_mfma_f32_16x16x32_bf16(ap0, bv[dt][0], oacc[dt], 0, 0, 0);
      oacc[dt] = __builtin_amdgcn_mfma_f32_16x16x32_bf16(ap1, bv[dt][1], oacc[dt], 0, 0, 0);
    }
  }
#pragma unroll
  for (int r = 0; r < 4; r++) {
#pragma unroll
    for (int ms = 1; ms < 16; ms <<= 1) lrow[r] += __shfl_xor(lrow[r], ms, 64);
  }
#pragma unroll
  for (int r = 0; r < 4; r++) {
    float invl = 1.0f / (lrow[r] - pad);
    int m = m0 + quad * 4 + r;
    u16* op = Ob + (size_t)m * DMODEL + h * 64;
#pragma unroll
    for (int dt = 0; dt < 4; dt++) op[dt * 16 + rl] = f2b(oacc[dt][r] * invl);
  }
}

// ---------------- GEGLU activation in-place: h1[r][i] = gate * gelu_exact(a) ----------------
__global__ void geglu(float* __restrict__ h1) {
  int row = blockIdx.y;
  int i = blockIdx.x * 256 + threadIdx.x;
  if (i < INNERD) {
    float* p = h1 + (size_t)row * FF1P;
    float a = p[i], gate = p[INNERD + i];
    float ge = 0.5f * a * (1.0f + erff(a * 0.70710678118654752f));
    p[i] = gate * ge;
  }
}

// ---------------- host ----------------
extern "C" void kernel_launch(void* const* d_in, const int* in_sizes, int n_in,
                              void* d_out, int out_size, void* d_ws, size_t ws_size,
                              hipStream_t stream) {
  const int*   x        = (const int*)d_in[0];
  const int*   cond_ids = (const int*)d_in[1];
  const float* token_emb      = (const float*)d_in[2];
  const float* pos_emb        = (const float*)d_in[3];
  const float* cond_token_emb = (const float*)d_in[4];
  const float* cond_pos_emb   = (const float*)d_in[5];
  const float* sa_g   = (const float*)d_in[6];
  const float* sa_wq  = (const float*)d_in[7];
  const float* sa_wkv = (const float*)d_in[8];
  const float* sa_null= (const float*)d_in[9];
  const float* sa_qs  = (const float*)d_in[10];
  const float* sa_ks  = (const float*)d_in[11];
  const float* sa_wo  = (const float*)d_in[12];
  const float* ca_g   = (const float*)d_in[13];
  const float* ca_wq  = (const float*)d_in[14];
  const float* ca_wkv = (const float*)d_in[15];
  const float* ca_null= (const float*)d_in[16];
  const float* ca_qs  = (const float*)d_in[17];
  const float* ca_ks  = (const float*)d_in[18];
  const float* ca_wo  = (const float*)d_in[19];
  const float* ff_g1  = (const float*)d_in[20];
  const float* ff_w1  = (const float*)d_in[21];
  const float* ff_g2  = (const float*)d_in[22];
  const float* ff_w2  = (const float*)d_in[23];
  const float* final_g  = (const float*)d_in[24];
  const float* w_logits = (const float*)d_in[25];

  char* base = (char*)d_ws; size_t off = 0;
  auto alloc = [&](size_t bytes) -> void* {
    void* r = base + off; off = (off + bytes + 255) & ~(size_t)255; return r;
  };
  u16* sa_qkv_t = (u16*)alloc((size_t)4 * 3072 * 1024 * 2);
  u16* sa_wo_t  = (u16*)alloc((size_t)4 * 1024 * 1024 * 2);
  u16* ca_wq_t  = (u16*)alloc((size_t)4 * 1024 * 1024 * 2);
  u16* ca_wkv_t = (u16*)alloc((size_t)4 * 2048 * 1024 * 2);
  u16* ca_wo_t  = (u16*)alloc((size_t)4 * 1024 * 1024 * 2);
  u16* ff_w1_t  = (u16*)alloc((size_t)4 * FF1P * 1024 * 2);
  u16* ff_w2_t  = (u16*)alloc((size_t)4 * 1024 * INNERP * 2);
  u16* logits_t = (u16*)alloc((size_t)VOCAB * 1024 * 2);
  float* h    = (float*)alloc((size_t)N_TOK * DMODEL * 4);
  u16*   ctxb = (u16*)alloc((size_t)NCTX * DMODEL * 2);
  u16*   xnb  = (u16*)alloc((size_t)N_TOK * INNERP * 2);
  float* qkv  = (float*)alloc((size_t)N_TOK * 3072 * 4);
  u16*   Qn   = (u16*)alloc((size_t)NHEAD * N_TOK * 64 * 2);
  u16*   Kn   = (u16*)alloc((size_t)NHEAD * 1600 * 64 * 2);
  u16*   Vt   = (u16*)alloc((size_t)NHEAD * 64 * 1600 * 2);
  u16*   ob   = (u16*)alloc((size_t)N_TOK * DMODEL * 2);
  float* h1   = (float*)alloc((size_t)N_TOK * FF1P * 4);
  (void)ws_size; (void)in_sizes; (void)n_in; (void)out_size;

  dim3 tb(32, 8);
  // weight convert+transpose (z = layer)
  conv_t<<<dim3(32, 32, 4), tb, 0, stream>>>(sa_wq,  sa_qkv_t,              1024, 1024, 1024, 1024, 1024LL*1024, 3072LL*1024);
  conv_t<<<dim3(32, 64, 4), tb, 0, stream>>>(sa_wkv, sa_qkv_t + 1024*1024,  1024, 2048, 1024, 2048, 1024LL*2048, 3072LL*1024);
  conv_t<<<dim3(32, 32, 4), tb, 0, stream>>>(sa_wo,  sa_wo_t,               1024, 1024, 1024, 1024, 1024LL*1024, 1024LL*1024);
  conv_t<<<dim3(32, 32, 4), tb, 0, stream>>>(ca_wq,  ca_wq_t,               1024, 1024, 1024, 1024, 1024LL*1024, 1024LL*1024);
  conv_t<<<dim3(32, 64, 4), tb, 0, stream>>>(ca_wkv, ca_wkv_t,              1024, 2048, 1024, 2048, 1024LL*2048, 2048LL*1024);
  conv_t<<<dim3(32, 32, 4), tb, 0, stream>>>(ca_wo,  ca_wo_t,               1024, 1024, 1024, 1024, 1024LL*1024, 1024LL*1024);
  conv_t<<<dim3(32, 172, 4), tb, 0, stream>>>(ff_w1, ff_w1_t,               1024, 5460, 1024, FF1P, 1024LL*5460, (long long)FF1P*1024);
  conv_t<<<dim3(86, 32, 4), tb, 0, stream>>>(ff_w2,  ff_w2_t,               INNERD, 1024, INNERP, 1024, (long long)INNERD*1024, 1024LL*INNERP);
  conv_t<<<dim3(32, 256, 1), tb, 0, stream>>>(w_logits, logits_t,           1024, VOCAB, 1024, VOCAB, 0, 0);

  // embeddings
  embed_img<<<dim3(N_TOK), dim3(256), 0, stream>>>(x, token_emb, pos_emb, h);
  embed_ctx<<<dim3(NCTX), dim3(256), 0, stream>>>(cond_ids, cond_token_emb, cond_pos_emb, ctxb);

  for (int l = 0; l < 4; l++) {
    const u16* sqkv = sa_qkv_t + (size_t)l * 3072 * 1024;
    const u16* swo  = sa_wo_t  + (size_t)l * 1024 * 1024;
    const u16* cwq  = ca_wq_t  + (size_t)l * 1024 * 1024;
    const u16* cwkv = ca_wkv_t + (size_t)l * 2048 * 1024;
    const u16* cwo  = ca_wo_t  + (size_t)l * 1024 * 1024;
    const u16* fw1  = ff_w1_t  + (size_t)l * FF1P * 1024;
    const u16* fw2  = ff_w2_t  + (size_t)l * 1024 * INNERP;

    // ---- self-attention ----
    ln_bf16<<<dim3(N_TOK), dim3(256), 0, stream>>>(h, DMODEL, sa_g + l * DMODEL, xnb, DMODEL, DMODEL, DMODEL);
    gemm_bt<false><<<dim3(12, 24), dim3(256), 0, stream>>>(xnb, sqkv, qkv, 3072, N_TOK, 3072, 1024, 1024, 1024);
    prep_q<<<dim3(384, NHEAD), dim3(256), 0, stream>>>(qkv, sa_qs + l * 64, Qn);
    prep_k<<<dim3(400, NHEAD), dim3(256), 0, stream>>>(qkv + 1024, sa_null + l * 2048, sa_ks + l * 64, Kn, 1537, 1600);
    transp_v<<<dim3(25, NHEAD), dim3(256), 0, stream>>>(qkv, sa_null + l * 2048, Vt, 1537, 1600);
    attn_mfma<<<dim3(24, NHEAD), dim3(256), 0, stream>>>(Qn, Kn, Vt, ob, 1600, 25, 63.0f);
    gemm_bt<true><<<dim3(12, 8), dim3(256), 0, stream>>>(ob, swo, h, 1024, N_TOK, 1024, 1024, 1024, 1024);

    // ---- cross-attention ----
    ln_bf16<<<dim3(N_TOK), dim3(256), 0, stream>>>(h, DMODEL, ca_g + l * DMODEL, xnb, DMODEL, DMODEL, DMODEL);
    gemm_bt<false><<<dim3(12, 8), dim3(256), 0, stream>>>(xnb, cwq, qkv, 3072, N_TOK, 1024, 1024, 1024, 1024);
    gemm_bt<false><<<dim3(4, 16), dim3(256), 0, stream>>>(ctxb, cwkv, qkv + 1024, 3072, NCTX, 2048, 1024, 1024, 1024);
    prep_q<<<dim3(384, NHEAD), dim3(256), 0, stream>>>(qkv, ca_qs + l * 64, Qn);
    prep_k<<<dim3(144, NHEAD), dim3(256), 0, stream>>>(qkv + 1024, ca_null + l * 2048, ca_ks + l * 64, Kn, 513, 576);
    transp_v<<<dim3(9, NHEAD), dim3(256), 0, stream>>>(qkv, ca_null + l * 2048, Vt, 513, 576);
    attn_mfma<<<dim3(24, NHEAD), dim3(256), 0, stream>>>(Qn, Kn, Vt, ob, 576, 9, 63.0f);
    gemm_bt<true><<<dim3(12, 8), dim3(256), 0, stream>>>(ob, cwo, h, 1024, N_TOK, 1024, 1024, 1024, 1024);

    // ---- GEGLU feedforward ----
    ln_bf16<<<dim3(N_TOK), dim3(256), 0, stream>>>(h, DMODEL, ff_g1 + l * DMODEL, xnb, DMODEL, DMODEL, DMODEL);
    gemm_bt<false><<<dim3(12, 43), dim3(256), 0, stream>>>(xnb, fw1, h1, FF1P, N_TOK, FF1P, 1024, 1024, 1024);
    geglu<<<dim3(11, N_TOK), dim3(256), 0, stream>>>(h1);
    ln_bf16<<<dim3(N_TOK), dim3(256), 0, stream>>>(h1, FF1P, ff_g2 + l * INNERD, xnb, INNERP, INNERD, INNERP);
    gemm_bt<true><<<dim3(12, 8), dim3(256), 0, stream>>>(xnb, fw2, h, 1024, N_TOK, 1024, INNERP, INNERP, INNERP);
  }

  // ---- final LN + logits ----
  ln_bf16<<<dim3(N_TOK), dim3(256), 0, stream>>>(h, DMODEL, final_g, xnb, DMODEL, DMODEL, DMODEL);
  gemm_bt<false><<<dim3(12, 64), dim3(256), 0, stream>>>(xnb, logits_t, (float*)d_out, VOCAB, N_TOK, VOCAB, 1024, 1024, 1024);
}

// Round 3
// 1884.832 us; speedup vs baseline: 1.6796x; 1.2234x over previous
//
#include <hip/hip_runtime.h>

// ---------------- types / helpers ----------------
typedef __attribute__((ext_vector_type(8))) short short8;
typedef __attribute__((ext_vector_type(4))) float f32x4;
typedef unsigned short u16;

#define N_TOK   1536
#define DMODEL  1024
#define NHEAD   16
#define DHEAD   64
#define NCTX    512
#define INNERD  2730
#define INNERP  2752   // K-padded inner
#define FF1P    5504   // N-padded 2*inner
#define VOCAB   8192

__device__ __forceinline__ u16 f2b(float f) {
  union { float f; unsigned u; } v; v.f = f;
  unsigned r = (v.u >> 16) & 1u;
  return (u16)((v.u + 0x7fffu + r) >> 16);
}

// ---------------- weight convert+transpose: f32 [z][K][Nw] -> bf16 [z][..][Kpad], out[n][k]=in[k][n]
// 64x64 tile, float4 global loads, short8 global stores.
__global__ __launch_bounds__(256) void conv_t(
    const float* __restrict__ in, u16* __restrict__ out,
    int K, int Nw, int Kpad, int Nbound, long long zin, long long zout)
{
  const float* inl = in + (size_t)blockIdx.z * zin;
  u16* outl = out + (size_t)blockIdx.z * zout;
  __shared__ float tile[64][65];
  int k0 = blockIdx.x * 64, n0 = blockIdx.y * 64;
  int tid = threadIdx.x;
  {
    int r = tid >> 4, c4 = (tid & 15) * 4;
#pragma unroll
    for (int j = 0; j < 4; j++) {
      int k = k0 + r + j * 16;
      float4 v = make_float4(0.f, 0.f, 0.f, 0.f);
      if (k < K && (n0 + c4) < Nw) v = *(const float4*)&inl[(size_t)k * Nw + n0 + c4];
      tile[r + j * 16][c4] = v.x; tile[r + j * 16][c4 + 1] = v.y;
      tile[r + j * 16][c4 + 2] = v.z; tile[r + j * 16][c4 + 3] = v.w;
    }
  }
  __syncthreads();
  {
    int nl = tid >> 2, kc = (tid & 3) * 16;
    int n = n0 + nl;
    if (n < Nbound) {
      u16 pk[16];
#pragma unroll
      for (int i = 0; i < 16; i++) pk[i] = f2b(tile[kc + i][nl]);
      u16* op = outl + (size_t)n * Kpad + k0 + kc;
      *(short8*)&op[0] = *(short8*)&pk[0];
      *(short8*)&op[8] = *(short8*)&pk[8];
    }
  }
}

// ---------------- embeddings ----------------
__global__ void embed_img(const int* __restrict__ x, const float* __restrict__ temb,
                          const float* __restrict__ pemb, float* __restrict__ h) {
  int n = blockIdx.x; int tok = x[n]; int d4 = threadIdx.x;
  float4 a = *(const float4*)&temb[(size_t)tok * DMODEL + d4 * 4];
  float4 b = *(const float4*)&pemb[(size_t)n * DMODEL + d4 * 4];
  float4 o; o.x = a.x + b.x; o.y = a.y + b.y; o.z = a.z + b.z; o.w = a.w + b.w;
  *(float4*)&h[(size_t)n * DMODEL + d4 * 4] = o;
}

__global__ void embed_ctx(const int* __restrict__ ids, const float* __restrict__ temb,
                          const float* __restrict__ pemb, u16* __restrict__ ctxb) {
  int n = blockIdx.x; int tok = ids[n]; int d4 = threadIdx.x;
  float4 a = *(const float4*)&temb[(size_t)tok * DMODEL + d4 * 4];
  float4 b = *(const float4*)&pemb[(size_t)n * DMODEL + d4 * 4];
  u16* o = ctxb + (size_t)n * DMODEL + d4 * 4;
  o[0] = f2b(a.x + b.x); o[1] = f2b(a.y + b.y); o[2] = f2b(a.z + b.z); o[3] = f2b(a.w + b.w);
}

// ---------------- LayerNorm -> bf16 ----------------
__global__ __launch_bounds__(256) void ln_bf16(
    const float* __restrict__ X, int ldin, const float* __restrict__ g,
    u16* __restrict__ Y, int ldout, int C, int Cpad)
{
  int row = blockIdx.x;
  const float* x = X + (size_t)row * ldin;
  float s = 0.f, sq = 0.f;
  for (int ci = threadIdx.x; ci < C; ci += 256) { float v = x[ci]; s += v; sq += v * v; }
#pragma unroll
  for (int m = 1; m < 64; m <<= 1) { s += __shfl_xor(s, m, 64); sq += __shfl_xor(sq, m, 64); }
  __shared__ float red[2][4];
  int w = threadIdx.x >> 6;
  if ((threadIdx.x & 63) == 0) { red[0][w] = s; red[1][w] = sq; }
  __syncthreads();
  s = red[0][0] + red[0][1] + red[0][2] + red[0][3];
  sq = red[1][0] + red[1][1] + red[1][2] + red[1][3];
  float mean = s / C;
  float var = sq / C - mean * mean;
  float rstd = rsqrtf(var + 1e-5f);
  u16* y = Y + (size_t)row * ldout;
  for (int ci = threadIdx.x; ci < C; ci += 256) y[ci] = f2b((x[ci] - mean) * rstd * g[ci]);
  for (int ci = C + threadIdx.x; ci < Cpad; ci += 256) y[ci] = 0;
}

// ---------------- GEMM: C(M,N) = A(M,K)bf16 @ Bt(N,K)bf16, 128x128 tile, BK=64 ----------------
// WMODE: 0 = store, 1 = read-modify-write (+=, single writer), 2 = atomicAdd (split-K)
template <int WMODE, int NSPLIT>
__global__ __launch_bounds__(256) void gemm_bt(
    const u16* __restrict__ A, const u16* __restrict__ Bt,
    float* __restrict__ C, int ldc, int M, int N, int K, int lda, int ldb)
{
  __shared__ __align__(16) short As[128 * 72];
  __shared__ __align__(16) short Bs[128 * 72];
  int tid = threadIdx.x;
  int bm = blockIdx.x, bn = blockIdx.y;
  int lane = tid & 63, w = tid >> 6;
  int wm = (w >> 1) * 64, wn = (w & 1) * 64;
  int rl = lane & 15, quad = lane >> 4;
  f32x4 acc[4][4];
#pragma unroll
  for (int i = 0; i < 4; i++)
#pragma unroll
    for (int j = 0; j < 4; j++) acc[i][j] = (f32x4)(0.f);
  const int rowA0 = bm * 128, rowB0 = bn * 128;
  int tiles = K >> 6;
  int t0 = (tiles * blockIdx.z) / NSPLIT, t1 = (tiles * (blockIdx.z + 1)) / NSPLIT;

  for (int kt = t0; kt < t1; kt++) {
    int k0 = kt * 64;
    __syncthreads();
#pragma unroll
    for (int i = 0; i < 4; i++) {
      int ch = tid + 256 * i;
      int r = ch >> 3, c8 = (ch & 7) * 8;
      *(short8*)&As[r * 72 + c8] = *(const short8*)(A + (size_t)(rowA0 + r) * lda + k0 + c8);
      *(short8*)&Bs[r * 72 + c8] = *(const short8*)(Bt + (size_t)(rowB0 + r) * ldb + k0 + c8);
    }
    __syncthreads();
#pragma unroll
    for (int kk = 0; kk < 64; kk += 32) {
      int kq = kk + quad * 8;
      short8 af[4], bfr[4];
#pragma unroll
      for (int t = 0; t < 4; t++) {
        af[t]  = *(const short8*)&As[(wm + t * 16 + rl) * 72 + kq];
        bfr[t] = *(const short8*)&Bs[(wn + t * 16 + rl) * 72 + kq];
      }
#pragma unroll
      for (int mt = 0; mt < 4; mt++)
#pragma unroll
        for (int nt = 0; nt < 4; nt++)
          acc[mt][nt] = __builtin_amdgcn_mfma_f32_16x16x32_bf16(af[mt], bfr[nt], acc[mt][nt], 0, 0, 0);
    }
  }
#pragma unroll
  for (int mt = 0; mt < 4; mt++)
#pragma unroll
    for (int nt = 0; nt < 4; nt++)
#pragma unroll
      for (int r = 0; r < 4; r++) {
        int row = rowA0 + wm + mt * 16 + quad * 4 + r;
        int col = rowB0 + wn + nt * 16 + rl;
        float* p = &C[(size_t)row * ldc + col];
        if (WMODE == 0) *p = acc[mt][nt][r];
        else if (WMODE == 1) *p += acc[mt][nt][r];
        else atomicAdd(p, acc[mt][nt][r]);
      }
}

// ---------------- fused K/V prep: null prepend, l2norm(k)*ks -> Kn[h][Lkp][64]; V transpose -> Vt[h][64][Lkp]
__global__ __launch_bounds__(256) void prep_kv(
    const float* __restrict__ kvb,   // k at kvb[(j-1)*3072 + h*64 + d], v at +1024
    const float* __restrict__ nullkv, const float* __restrict__ ks,
    u16* __restrict__ Kn, u16* __restrict__ Vt, int Lk, int Lkp)
{
  int h = blockIdx.y, j0 = blockIdx.x * 64;
  int tid = threadIdx.x, w = tid >> 6, d = tid & 63;
  float ksd = ks[d];
  // K phase: 16 keys per wave, full-wave l2norm per key
#pragma unroll 4
  for (int r = 0; r < 16; r++) {
    int j = j0 + w * 16 + r;
    float k = 0.f;
    if (j == 0) k = nullkv[h * 64 + d];
    else if (j < Lk) k = kvb[(size_t)(j - 1) * 3072 + h * 64 + d];
    float ssq = k * k;
#pragma unroll
    for (int ms = 1; ms < 64; ms <<= 1) ssq += __shfl_xor(ssq, ms, 64);
    float kn = k * (1.0f / fmaxf(sqrtf(ssq), 1e-12f)) * ksd;
    Kn[((size_t)h * Lkp + j) * 64 + d] = f2b(kn);
  }
  // V phase: transpose 64x64 via LDS
  __shared__ float tile[64][65];
  {
    int jl = tid >> 2, c16 = (tid & 3) * 16;
    int j = j0 + jl;
#pragma unroll
    for (int i4 = 0; i4 < 4; i4++) {
      float4 v = make_float4(0.f, 0.f, 0.f, 0.f);
      if (j == 0) v = *(const float4*)&nullkv[NHEAD * 64 + h * 64 + c16 + i4 * 4];
      else if (j < Lk) v = *(const float4*)&kvb[(size_t)(j - 1) * 3072 + 1024 + h * 64 + c16 + i4 * 4];
      tile[jl][c16 + i4 * 4] = v.x; tile[jl][c16 + i4 * 4 + 1] = v.y;
      tile[jl][c16 + i4 * 4 + 2] = v.z; tile[jl][c16 + i4 * 4 + 3] = v.w;
    }
  }
  __syncthreads();
  {
    int dd = tid >> 2, jc = (tid & 3) * 16;
    u16 pk[16];
#pragma unroll
    for (int i = 0; i < 16; i++) pk[i] = f2b(tile[jc + i][dd]);
    u16* op = Vt + ((size_t)h * 64 + dd) * Lkp + j0 + jc;
    *(short8*)&op[0] = *(short8*)&pk[0];
    *(short8*)&op[8] = *(short8*)&pk[8];
  }
}

// ---------------- MFMA flash attention, 2 waves x 16 q-rows, XCD head-clustered grid ----
__global__ __launch_bounds__(128) void attn_mfma(
    const float* __restrict__ qkv, const float* __restrict__ qs,
    const u16* __restrict__ Kn, const u16* __restrict__ Vt,
    u16* __restrict__ Ob, int Lkp, int nk, float pad)
{
  __shared__ __align__(16) short Ps[2 * 16 * 72];
  int tid = threadIdx.x, w = tid >> 6, lane = tid & 63;
  int rl = lane & 15, quad = lane >> 4;
  int b = blockIdx.x;
  int h = (b & 7) * 2 + ((b >> 3) & 1);   // XCD-clustered: XCD x -> heads {2x,2x+1}
  int qt = b >> 4;
  int m0 = qt * 32 + w * 16;
  short* Pw = Ps + w * 16 * 72;

  // fused q l2norm * qs * 8 -> bf16 A-frags
  short8 aq[2];
  {
    const float* qp = qkv + (size_t)(m0 + rl) * 3072 + h * 64;
    float qv[16];
    float ssq = 0.f;
#pragma unroll
    for (int cb = 0; cb < 2; cb++) {
      float4 t0 = *(const float4*)&qp[cb * 32 + quad * 8];
      float4 t1 = *(const float4*)&qp[cb * 32 + quad * 8 + 4];
      qv[cb * 8 + 0] = t0.x; qv[cb * 8 + 1] = t0.y; qv[cb * 8 + 2] = t0.z; qv[cb * 8 + 3] = t0.w;
      qv[cb * 8 + 4] = t1.x; qv[cb * 8 + 5] = t1.y; qv[cb * 8 + 6] = t1.z; qv[cb * 8 + 7] = t1.w;
      ssq += t0.x * t0.x + t0.y * t0.y + t0.z * t0.z + t0.w * t0.w;
      ssq += t1.x * t1.x + t1.y * t1.y + t1.z * t1.z + t1.w * t1.w;
    }
    ssq += __shfl_xor(ssq, 16, 64);
    ssq += __shfl_xor(ssq, 32, 64);
    float inv = 8.0f / fmaxf(sqrtf(ssq), 1e-12f);
    u16 pk[16];
#pragma unroll
    for (int cb = 0; cb < 2; cb++) {
      float4 s0 = *(const float4*)&qs[cb * 32 + quad * 8];
      float4 s1 = *(const float4*)&qs[cb * 32 + quad * 8 + 4];
      pk[cb * 8 + 0] = f2b(qv[cb * 8 + 0] * inv * s0.x);
      pk[cb * 8 + 1] = f2b(qv[cb * 8 + 1] * inv * s0.y);
      pk[cb * 8 + 2] = f2b(qv[cb * 8 + 2] * inv * s0.z);
      pk[cb * 8 + 3] = f2b(qv[cb * 8 + 3] * inv * s0.w);
      pk[cb * 8 + 4] = f2b(qv[cb * 8 + 4] * inv * s1.x);
      pk[cb * 8 + 5] = f2b(qv[cb * 8 + 5] * inv * s1.y);
      pk[cb * 8 + 6] = f2b(qv[cb * 8 + 6] * inv * s1.z);
      pk[cb * 8 + 7] = f2b(qv[cb * 8 + 7] * inv * s1.w);
    }
    aq[0] = *(short8*)&pk[0];
    aq[1] = *(short8*)&pk[8];
  }

  const u16* Kh = Kn + (size_t)h * Lkp * 64;
  const u16* Vh = Vt + (size_t)h * 64 * Lkp;
  f32x4 oacc[4];
#pragma unroll
  for (int dt = 0; dt < 4; dt++) oacc[dt] = (f32x4)(0.f);
  float lrow[4] = {0.f, 0.f, 0.f, 0.f};

  for (int kt = 0; kt < nk; kt++) {
    int j0 = kt * 64;
    short8 bk[4][2], bv[4][2];
#pragma unroll
    for (int nt = 0; nt < 4; nt++)
#pragma unroll
      for (int kc = 0; kc < 2; kc++)
        bk[nt][kc] = *(const short8*)(Kh + (size_t)(j0 + nt * 16 + rl) * 64 + kc * 32 + quad * 8);
#pragma unroll
    for (int dt = 0; dt < 4; dt++)
#pragma unroll
      for (int kc = 0; kc < 2; kc++)
        bv[dt][kc] = *(const short8*)(Vh + (size_t)(dt * 16 + rl) * Lkp + j0 + kc * 32 + quad * 8);

    f32x4 sacc[4];
#pragma unroll
    for (int nt = 0; nt < 4; nt++) sacc[nt] = (f32x4)(0.f);
#pragma unroll
    for (int kc = 0; kc < 2; kc++)
#pragma unroll
      for (int nt = 0; nt < 4; nt++)
        sacc[nt] = __builtin_amdgcn_mfma_f32_16x16x32_bf16(aq[kc], bk[nt][kc], sacc[nt], 0, 0, 0);

#pragma unroll
    for (int nt = 0; nt < 4; nt++)
#pragma unroll
      for (int r = 0; r < 4; r++) {
        float p = __expf(sacc[nt][r]);
        lrow[r] += p;
        Pw[(quad * 4 + r) * 72 + nt * 16 + rl] = (short)f2b(p);
      }
    __asm volatile("s_waitcnt lgkmcnt(0)" ::: "memory");
    short8 ap0 = *(const short8*)&Pw[rl * 72 + quad * 8];
    short8 ap1 = *(const short8*)&Pw[rl * 72 + 32 + quad * 8];
#pragma unroll
    for (int dt = 0; dt < 4; dt++) {
      oacc[dt] = __builtin_amdgcn_mfma_f32_16x16x32_bf16(ap0, bv[dt][0], oacc[dt], 0, 0, 0);
      oacc[dt] = __builtin_amdgcn_mfma_f32_16x16x32_bf16(ap1, bv[dt][1], oacc[dt], 0, 0, 0);
    }
  }
#pragma unroll
  for (int r = 0; r < 4; r++) {
#pragma unroll
    for (int ms = 1; ms < 16; ms <<= 1) lrow[r] += __shfl_xor(lrow[r], ms, 64);
  }
#pragma unroll
  for (int r = 0; r < 4; r++) {
    float invl = 1.0f / (lrow[r] - pad);
    int m = m0 + quad * 4 + r;
    u16* op = Ob + (size_t)m * DMODEL + h * 64;
#pragma unroll
    for (int dt = 0; dt < 4; dt++) op[dt * 16 + rl] = f2b(oacc[dt][r] * invl);
  }
}

// ---------------- fused GEGLU + LayerNorm -> bf16 (row = token) ----------------
__global__ __launch_bounds__(256) void geglu_ln(
    const float* __restrict__ h1, const float* __restrict__ g2, u16* __restrict__ Y)
{
  int row = blockIdx.x;
  const float* p = h1 + (size_t)row * FF1P;
  float act[11];
  float s = 0.f, sq = 0.f;
#pragma unroll
  for (int t = 0; t < 11; t++) {
    int i = threadIdx.x + t * 256;
    float v = 0.f;
    if (i < INNERD) {
      float a = p[i], gate = p[INNERD + i];
      float ge = 0.5f * a * (1.0f + erff(a * 0.70710678118654752f));
      v = gate * ge;
    }
    act[t] = v; s += v; sq += v * v;
  }
#pragma unroll
  for (int m = 1; m < 64; m <<= 1) { s += __shfl_xor(s, m, 64); sq += __shfl_xor(sq, m, 64); }
  __shared__ float red[2][4];
  int w = threadIdx.x >> 6;
  if ((threadIdx.x & 63) == 0) { red[0][w] = s; red[1][w] = sq; }
  __syncthreads();
  s = red[0][0] + red[0][1] + red[0][2] + red[0][3];
  sq = red[1][0] + red[1][1] + red[1][2] + red[1][3];
  float mean = s / INNERD;
  float var = sq / INNERD - mean * mean;
  float rstd = rsqrtf(var + 1e-5f);
  u16* y = Y + (size_t)row * INNERP;
#pragma unroll
  for (int t = 0; t < 11; t++) {
    int i = threadIdx.x + t * 256;
    if (i < INNERD) y[i] = f2b((act[t] - mean) * rstd * g2[i]);
  }
  if (threadIdx.x < INNERP - INNERD) y[INNERD + threadIdx.x] = 0;
}

// ---------------- host ----------------
extern "C" void kernel_launch(void* const* d_in, const int* in_sizes, int n_in,
                              void* d_out, int out_size, void* d_ws, size_t ws_size,
                              hipStream_t stream) {
  const int*   x        = (const int*)d_in[0];
  const int*   cond_ids = (const int*)d_in[1];
  const float* token_emb      = (const float*)d_in[2];
  const float* pos_emb        = (const float*)d_in[3];
  const float* cond_token_emb = (const float*)d_in[4];
  const float* cond_pos_emb   = (const float*)d_in[5];
  const float* sa_g   = (const float*)d_in[6];
  const float* sa_wq  = (const float*)d_in[7];
  const float* sa_wkv = (const float*)d_in[8];
  const float* sa_null= (const float*)d_in[9];
  const float* sa_qs  = (const float*)d_in[10];
  const float* sa_ks  = (const float*)d_in[11];
  const float* sa_wo  = (const float*)d_in[12];
  const float* ca_g   = (const float*)d_in[13];
  const float* ca_wq  = (const float*)d_in[14];
  const float* ca_wkv = (const float*)d_in[15];
  const float* ca_null= (const float*)d_in[16];
  const float* ca_qs  = (const float*)d_in[17];
  const float* ca_ks  = (const float*)d_in[18];
  const float* ca_wo  = (const float*)d_in[19];
  const float* ff_g1  = (const float*)d_in[20];
  const float* ff_w1  = (const float*)d_in[21];
  const float* ff_g2  = (const float*)d_in[22];
  const float* ff_w2  = (const float*)d_in[23];
  const float* final_g  = (const float*)d_in[24];
  const float* w_logits = (const float*)d_in[25];

  char* base = (char*)d_ws; size_t off = 0;
  auto alloc = [&](size_t bytes) -> void* {
    void* r = base + off; off = (off + bytes + 255) & ~(size_t)255; return r;
  };
  u16* sa_qkv_t = (u16*)alloc((size_t)4 * 3072 * 1024 * 2);
  u16* sa_wo_t  = (u16*)alloc((size_t)4 * 1024 * 1024 * 2);
  u16* ca_wq_t  = (u16*)alloc((size_t)4 * 1024 * 1024 * 2);
  u16* ca_wkv_t = (u16*)alloc((size_t)4 * 2048 * 1024 * 2);
  u16* ca_wo_t  = (u16*)alloc((size_t)4 * 1024 * 1024 * 2);
  u16* ff_w1_t  = (u16*)alloc((size_t)4 * FF1P * 1024 * 2);
  u16* ff_w2_t  = (u16*)alloc((size_t)4 * 1024 * INNERP * 2);
  u16* logits_t = (u16*)alloc((size_t)VOCAB * 1024 * 2);
  float* h    = (float*)alloc((size_t)N_TOK * DMODEL * 4);
  u16*   ctxb = (u16*)alloc((size_t)NCTX * DMODEL * 2);
  u16*   xnb  = (u16*)alloc((size_t)N_TOK * INNERP * 2);
  float* qkv  = (float*)alloc((size_t)N_TOK * 3072 * 4);
  u16*   Kn   = (u16*)alloc((size_t)NHEAD * 1600 * 64 * 2);
  u16*   Vt   = (u16*)alloc((size_t)NHEAD * 64 * 1600 * 2);
  u16*   ob   = (u16*)alloc((size_t)N_TOK * DMODEL * 2);
  float* h1   = (float*)alloc((size_t)N_TOK * FF1P * 4);
  (void)ws_size; (void)in_sizes; (void)n_in; (void)out_size;

  // weight convert+transpose (z = layer); grids in 64x64 tiles
  conv_t<<<dim3(16, 16, 4), 256, 0, stream>>>(sa_wq,  sa_qkv_t,              1024, 1024, 1024, 1024, 1024LL*1024, 3072LL*1024);
  conv_t<<<dim3(16, 32, 4), 256, 0, stream>>>(sa_wkv, sa_qkv_t + 1024*1024,  1024, 2048, 1024, 2048, 1024LL*2048, 3072LL*1024);
  conv_t<<<dim3(16, 16, 4), 256, 0, stream>>>(sa_wo,  sa_wo_t,               1024, 1024, 1024, 1024, 1024LL*1024, 1024LL*1024);
  conv_t<<<dim3(16, 16, 4), 256, 0, stream>>>(ca_wq,  ca_wq_t,               1024, 1024, 1024, 1024, 1024LL*1024, 1024LL*1024);
  conv_t<<<dim3(16, 32, 4), 256, 0, stream>>>(ca_wkv, ca_wkv_t,              1024, 2048, 1024, 2048, 1024LL*2048, 2048LL*1024);
  conv_t<<<dim3(16, 16, 4), 256, 0, stream>>>(ca_wo,  ca_wo_t,               1024, 1024, 1024, 1024, 1024LL*1024, 1024LL*1024);
  conv_t<<<dim3(16, 86, 4), 256, 0, stream>>>(ff_w1,  ff_w1_t,               1024, 5460, 1024, FF1P, 1024LL*5460, (long long)FF1P*1024);
  conv_t<<<dim3(43, 16, 4), 256, 0, stream>>>(ff_w2,  ff_w2_t,               INNERD, 1024, INNERP, 1024, (long long)INNERD*1024, 1024LL*INNERP);
  conv_t<<<dim3(16, 128, 1), 256, 0, stream>>>(w_logits, logits_t,           1024, VOCAB, 1024, VOCAB, 0, 0);

  // embeddings
  embed_img<<<dim3(N_TOK), dim3(256), 0, stream>>>(x, token_emb, pos_emb, h);
  embed_ctx<<<dim3(NCTX), dim3(256), 0, stream>>>(cond_ids, cond_token_emb, cond_pos_emb, ctxb);

  for (int l = 0; l < 4; l++) {
    const u16* sqkv = sa_qkv_t + (size_t)l * 3072 * 1024;
    const u16* swo  = sa_wo_t  + (size_t)l * 1024 * 1024;
    const u16* cwq  = ca_wq_t  + (size_t)l * 1024 * 1024;
    const u16* cwkv = ca_wkv_t + (size_t)l * 2048 * 1024;
    const u16* cwo  = ca_wo_t  + (size_t)l * 1024 * 1024;
    const u16* fw1  = ff_w1_t  + (size_t)l * FF1P * 1024;
    const u16* fw2  = ff_w2_t  + (size_t)l * 1024 * INNERP;

    // ---- self-attention ----
    ln_bf16<<<dim3(N_TOK), dim3(256), 0, stream>>>(h, DMODEL, sa_g + l * DMODEL, xnb, DMODEL, DMODEL, DMODEL);
    gemm_bt<0, 1><<<dim3(12, 24, 1), dim3(256), 0, stream>>>(xnb, sqkv, qkv, 3072, N_TOK, 3072, 1024, 1024, 1024);
    prep_kv<<<dim3(25, NHEAD), dim3(256), 0, stream>>>(qkv + 1024, sa_null + l * 2048, sa_ks + l * 64, Kn, Vt, 1537, 1600);
    attn_mfma<<<dim3(768), dim3(128), 0, stream>>>(qkv, sa_qs + l * 64, Kn, Vt, ob, 1600, 25, 63.0f);
    gemm_bt<2, 4><<<dim3(12, 8, 4), dim3(256), 0, stream>>>(ob, swo, h, 1024, N_TOK, 1024, 1024, 1024, 1024);

    // ---- cross-attention ----
    ln_bf16<<<dim3(N_TOK), dim3(256), 0, stream>>>(h, DMODEL, ca_g + l * DMODEL, xnb, DMODEL, DMODEL, DMODEL);
    hipMemsetAsync(qkv, 0, (size_t)N_TOK * 3072 * 4, stream);
    gemm_bt<2, 4><<<dim3(12, 8, 4), dim3(256), 0, stream>>>(xnb, cwq, qkv, 3072, N_TOK, 1024, 1024, 1024, 1024);
    gemm_bt<2, 4><<<dim3(4, 16, 4), dim3(256), 0, stream>>>(ctxb, cwkv, qkv + 1024, 3072, NCTX, 2048, 1024, 1024, 1024);
    prep_kv<<<dim3(9, NHEAD), dim3(256), 0, stream>>>(qkv + 1024, ca_null + l * 2048, ca_ks + l * 64, Kn, Vt, 513, 576);
    attn_mfma<<<dim3(768), dim3(128), 0, stream>>>(qkv, ca_qs + l * 64, Kn, Vt, ob, 576, 9, 63.0f);
    gemm_bt<2, 4><<<dim3(12, 8, 4), dim3(256), 0, stream>>>(ob, cwo, h, 1024, N_TOK, 1024, 1024, 1024, 1024);

    // ---- GEGLU feedforward ----
    ln_bf16<<<dim3(N_TOK), dim3(256), 0, stream>>>(h, DMODEL, ff_g1 + l * DMODEL, xnb, DMODEL, DMODEL, DMODEL);
    gemm_bt<0, 1><<<dim3(12, 43, 1), dim3(256), 0, stream>>>(xnb, fw1, h1, FF1P, N_TOK, FF1P, 1024, 1024, 1024);
    geglu_ln<<<dim3(N_TOK), dim3(256), 0, stream>>>(h1, ff_g2 + l * INNERD, xnb);
    gemm_bt<2, 4><<<dim3(12, 8, 4), dim3(256), 0, stream>>>(xnb, fw2, h, 1024, N_TOK, 1024, INNERP, INNERP, INNERP);
  }

  // ---- final LN + logits ----
  ln_bf16<<<dim3(N_TOK), dim3(256), 0, stream>>>(h, DMODEL, final_g, xnb, DMODEL, DMODEL, DMODEL);
  gemm_bt<0, 1><<<dim3(12, 64, 1), dim3(256), 0, stream>>>(xnb, logits_t, (float*)d_out, VOCAB, N_TOK, VOCAB, 1024, 1024, 1024);
}